// Round 5
// baseline (500.854 us; speedup 1.0000x reference)
//
#include <hip/hip_runtime.h>
#include <hip/hip_bf16.h>
#include <hip/hip_fp8.h>

// MatchingLayer: B=8, S=2048, H=1024
//   scores = (X X^T)/32 -> mask -> softmax -> context = P X
//   matching = [X|context] @ W + b -> LayerNorm
// Round-5 theory: this problem is TLP/occupancy-gated, not interleave-gated.
//   gemm1: round-0 128^2 / 256-thr kernel (proven fastest, ~3 blocks/CU).
//   gemm2/3: 256x128 tile, 2 LDS buffers (48 KB), 512-block grids -> 2
//   blocks/CU; minimum-2-phase counted loop (stage(t+1); reads(t); MFMA;
//   vmcnt(0); barrier) with co-resident block hiding the drain.
// T2 XOR swizzle pre-applied on the global source (rule #21).
// WORKSPACE REQUIREMENT: 172,032,000 bytes (X8 aliases CTX region).

typedef unsigned short ushort_t;
typedef __attribute__((ext_vector_type(8))) short short8;
typedef __attribute__((ext_vector_type(4))) float float4v;

__device__ inline float b2f(unsigned int u) {
    union { unsigned int i; float f; } v; v.i = u << 16; return v.f;
}
__device__ inline ushort_t f2b(float f) {
    __hip_bfloat16 h = __float2bfloat16(f);
    return __builtin_bit_cast(ushort_t, h);
}
__device__ inline unsigned char f2e4(float f) {
    return __hip_fp8_e4m3(f).__x;
}

// async global->LDS DMA, 16B per lane; lds base wave-uniform, lane i -> lds+i*16.
__device__ inline void gload_lds16(const void* g, void* lds) {
    __builtin_amdgcn_global_load_lds(
        (const __attribute__((address_space(1))) unsigned int*)g,
        (__attribute__((address_space(3))) unsigned int*)lds, 16, 0, 0);
}

// ---------------- bf16 GEMM:  C[m][n] = sum_k A[m][k]*B[n][k] ----------------
// 256x128 tile, BK=32, 2 LDS buffers x (A 16KB + B 8KB) = 48 KiB,
// 512 thr = 8 waves (2Mx4N), per-wave C = 128x32 = 8x2 frags (acc -> AGPR).
// Minimum-2-phase counted loop; 2 blocks/CU co-residency hides the per-step
// vmcnt(0)+barrier drain (m97/m114 mechanism).
// A dual-sourced at kSplit (for [X|ctx] concat).
// EPI 2: v / rowsum[row] -> bf16    EPI 3: v + bias[col] -> bf16
template<int EPI>
__global__ __launch_bounds__(512, 4)
void gemm_bt(const ushort_t* __restrict__ A, const ushort_t* __restrict__ A2, int kSplit,
             const ushort_t* __restrict__ B,
             int M, int N, int K, int lda, int ldb, int ldc,
             long aBS, long bBS, long cBS,
             const float* __restrict__ rowsum,
             const float* __restrict__ bias,
             ushort_t* __restrict__ outb)
{
    // 2 buffers x 12288 ushorts (A 8192 ush = 16 KB, B 4096 ush = 8 KB)
    __shared__ __align__(16) ushort_t smem[2 * 12288];

    const int tid = threadIdx.x;
    const int z = blockIdx.z;
    A  += (size_t)z * aBS;
    A2 += (size_t)z * aBS;
    B  += (size_t)z * bBS;
    if (EPI == 2) rowsum += (size_t)z * M;
    outb += (size_t)z * cBS;

    const int bm = blockIdx.x * 256;
    const int bn = blockIdx.y * 128;
    const int w = tid >> 6, lane = tid & 63;
    const int wm = (w >> 2) * 128, wn = (w & 3) * 32;
    const int q = lane >> 4, l15 = lane & 15;
    // staging: 512 threads x 16B = 8 KB/round = 128 rows of 64 B
    const int srow = tid >> 2;                                // 0..127
    const int schunk = ((tid & 3) ^ ((tid >> 3) & 3)) * 8;    // pre-swizzled src chunk (elems)
    // per-wave LDS dest base (ushorts): wave w covers rows w*16..w*16+15
    const int wbase = w * 512;

    float4v acc[8][2];
#pragma unroll
    for (int i = 0; i < 8; i++)
#pragma unroll
        for (int j = 0; j < 2; j++) acc[i][j] = (float4v){0.f, 0.f, 0.f, 0.f};

    const int NT = K >> 5;   // K-steps of 32

    // stage K-step T into buf[T&1]: A rows 0..127, A rows 128..255, B rows 0..127
#define STAGE(T) do {                                                                \
        const int k0_ = (T) * 32;                                                    \
        const ushort_t* aS_ = A; int ka_ = k0_;                                      \
        if (k0_ >= kSplit) { aS_ = A2; ka_ = k0_ - kSplit; }                         \
        ushort_t* buf_ = &smem[((T) & 1) * 12288];                                   \
        gload_lds16(aS_ + (size_t)(bm + srow)       * lda + ka_ + schunk,            \
                    buf_ + wbase);                                                   \
        gload_lds16(aS_ + (size_t)(bm + 128 + srow) * lda + ka_ + schunk,            \
                    buf_ + 4096 + wbase);                                            \
        gload_lds16(B   + (size_t)(bn + srow)       * ldb + k0_ + schunk,            \
                    buf_ + 8192 + wbase);                                            \
    } while (0)

    STAGE(0);
    asm volatile("s_waitcnt vmcnt(0)" ::: "memory");
    __builtin_amdgcn_s_barrier();

    for (int t = 0; t < NT; ++t) {
        if (t + 1 < NT) STAGE(t + 1);

        const ushort_t* bufA = &smem[(t & 1) * 12288];
        const ushort_t* bufB = bufA + 8192;
        short8 af[4], bf[2];
#pragma unroll
        for (int ni = 0; ni < 2; ni++) {
            const int r = wn + ni * 16 + l15;
            bf[ni] = *(const short8*)(&bufB[r * 32 + ((q ^ ((r >> 1) & 3)) << 3)]);
        }
        // mi-half 0: rows wm+0..63
#pragma unroll
        for (int mi = 0; mi < 4; mi++) {
            const int r = wm + mi * 16 + l15;
            af[mi] = *(const short8*)(&bufA[r * 32 + ((q ^ ((r >> 1) & 3)) << 3)]);
        }
        __builtin_amdgcn_s_setprio(1);
#pragma unroll
        for (int mi = 0; mi < 4; mi++)
#pragma unroll
            for (int ni = 0; ni < 2; ni++)
                acc[mi][ni] = __builtin_amdgcn_mfma_f32_16x16x32_bf16(
                    af[mi], bf[ni], acc[mi][ni], 0, 0, 0);
        __builtin_amdgcn_s_setprio(0);
        // mi-half 1: rows wm+64..127 (reuse af regs)
#pragma unroll
        for (int mi = 0; mi < 4; mi++) {
            const int r = wm + 64 + mi * 16 + l15;
            af[mi] = *(const short8*)(&bufA[r * 32 + ((q ^ ((r >> 1) & 3)) << 3)]);
        }
        __builtin_amdgcn_s_setprio(1);
#pragma unroll
        for (int mi = 0; mi < 4; mi++)
#pragma unroll
            for (int ni = 0; ni < 2; ni++)
                acc[4 + mi][ni] = __builtin_amdgcn_mfma_f32_16x16x32_bf16(
                    af[mi], bf[ni], acc[4 + mi][ni], 0, 0, 0);
        __builtin_amdgcn_s_setprio(0);

        // next buffer landed before all waves cross
        asm volatile("s_waitcnt vmcnt(0)" ::: "memory");
        __builtin_amdgcn_s_barrier();
    }
#undef STAGE

    // D layout (m89): col = lane&15, row = (lane>>4)*4 + reg
#pragma unroll
    for (int mi = 0; mi < 8; mi++) {
#pragma unroll
        for (int r = 0; r < 4; r++) {
            const int row = bm + wm + mi * 16 + q * 4 + r;
            const size_t ro = (size_t)row * ldc;
            float rsinv = 1.f;
            if (EPI == 2) rsinv = 1.0f / rowsum[row];
#pragma unroll
            for (int ni = 0; ni < 2; ni++) {
                const int col = bn + wn + ni * 16 + l15;
                float v = acc[mi][ni][r];
                if (EPI == 2) outb[ro + col] = f2b(v * rsinv);
                else          outb[ro + col] = f2b(v + bias[col]);
            }
        }
    }
}

// ---------------- fp8 GEMM1: E = exp(mask(scale * X X^T)), rowsum ----------------
// Round-0 kernel (proven fastest): 128^2 tile, BK=128, 256 thr, 32 KB LDS,
// ~3 blocks/CU give the TLP that hides the barrier drain and the epilogue.
__global__ __launch_bounds__(256, 2)
void gemm1_fp8(const unsigned char* __restrict__ X8,
               const float* __restrict__ mask,
               float* __restrict__ rowsum,
               ushort_t* __restrict__ E)
{
    __shared__ __align__(16) unsigned char As[128 * 128];
    __shared__ __align__(16) unsigned char Bs[128 * 128];

    const int tid = threadIdx.x;
    const int z = blockIdx.z;
    const unsigned char* Xz = X8 + (size_t)z * 2048 * 1024;
    const float* mz = mask + (size_t)z * 2048 * 2048;
    float* rsz = rowsum + (size_t)z * 2048;
    ushort_t* Ez = E + (size_t)z * 2048 * 2048;

    const int bm = blockIdx.x * 128;
    const int bn = blockIdx.y * 128;
    const int wave = tid >> 6, lane = tid & 63;
    const int wm = (wave >> 1) * 64, wn = (wave & 1) * 64;
    const int q = lane >> 4, l15 = lane & 15;
    const int rx = l15 & 7;
    const int lrow = lane >> 3;
    const int cswz = (lane & 7) ^ lrow;       // 16B chunk 0..7 within 128B row

    float4v acc[4][4];
#pragma unroll
    for (int i = 0; i < 4; i++)
#pragma unroll
        for (int j = 0; j < 4; j++) acc[i][j] = (float4v){0.f, 0.f, 0.f, 0.f};

    for (int k0 = 0; k0 < 1024; k0 += 128) {
        // stage 128 rows x 128 B per matrix: 16 passes of 8 rows, wave w -> p=w*4..w*4+3
#pragma unroll
        for (int j = 0; j < 4; j++) {
            const int p = wave * 4 + j;
            const int ro = p * 8 + lrow;
            gload_lds16(Xz + (size_t)(bm + ro) * 1024 + k0 + cswz * 16, &As[p * 1024]);
            gload_lds16(Xz + (size_t)(bn + ro) * 1024 + k0 + cswz * 16, &Bs[p * 1024]);
        }
        __syncthreads();
#pragma unroll
        for (int kk = 0; kk < 128; kk += 32) {
            const int g = (kk >> 3) + q;                      // 8B granule 0..15
            const int co = (((g >> 1) ^ rx) << 4) + ((g & 1) << 3);
            long af[4], bfv[4];
#pragma unroll
            for (int mi = 0; mi < 4; mi++)
                af[mi] = *(const long*)(&As[(wm + mi * 16 + l15) * 128 + co]);
#pragma unroll
            for (int ni = 0; ni < 4; ni++)
                bfv[ni] = *(const long*)(&Bs[(wn + ni * 16 + l15) * 128 + co]);
#pragma unroll
            for (int mi = 0; mi < 4; mi++)
#pragma unroll
                for (int ni = 0; ni < 4; ni++)
                    acc[mi][ni] = __builtin_amdgcn_mfma_f32_16x16x32_fp8_fp8(
                        af[mi], bfv[ni], acc[mi][ni], 0, 0, 0);
        }
        __syncthreads();
    }

    const float scale = 0.03125f;  // 1/sqrt(1024)
#pragma unroll
    for (int mi = 0; mi < 4; mi++) {
#pragma unroll
        for (int r = 0; r < 4; r++) {
            const int row = bm + wm + mi * 16 + q * 4 + r;
            const size_t ro = (size_t)row * 2048;
            float s = 0.f;
#pragma unroll
            for (int ni = 0; ni < 4; ni++) {
                const int col = bn + wn + ni * 16 + l15;
                const float m = mz[ro + col];
                float v = __expf(acc[mi][ni][r] * scale * m - 1e9f * (1.0f - m));
                s += v;
                Ez[ro + col] = f2b(v);
            }
            s += __shfl_xor(s, 8);
            s += __shfl_xor(s, 4);
            s += __shfl_xor(s, 2);
            s += __shfl_xor(s, 1);
            if (l15 == 0) atomicAdd(&rsz[row], s);
        }
    }
}

// fp32 [R][C] (batched z) -> outT bf16 [C][R]; optional outS bf16 + outQ fp8 [R][C].
__global__ __launch_bounds__(256)
void conv_trans(const float* __restrict__ in, ushort_t* __restrict__ outT,
                ushort_t* __restrict__ outS, unsigned char* __restrict__ outQ,
                int R, int C)
{
    __shared__ float tile[64][65];
    const int tx = threadIdx.x & 15, ty = threadIdx.x >> 4;
    const size_t zoff = (size_t)blockIdx.z * R * C;
    const int r0 = blockIdx.y * 64, c0 = blockIdx.x * 64;
#pragma unroll
    for (int j = 0; j < 4; j++) {
        const int r = ty + j * 16;
        const float4 v = *(const float4*)(in + zoff + (size_t)(r0 + r) * C + c0 + tx * 4);
        tile[r][tx * 4 + 0] = v.x;
        tile[r][tx * 4 + 1] = v.y;
        tile[r][tx * 4 + 2] = v.z;
        tile[r][tx * 4 + 3] = v.w;
        if (outS) {
            ushort4 o;
            o.x = f2b(v.x); o.y = f2b(v.y); o.z = f2b(v.z); o.w = f2b(v.w);
            *(ushort4*)(outS + zoff + (size_t)(r0 + r) * C + c0 + tx * 4) = o;
            uchar4 p;
            p.x = f2e4(v.x); p.y = f2e4(v.y); p.z = f2e4(v.z); p.w = f2e4(v.w);
            *(uchar4*)(outQ + zoff + (size_t)(r0 + r) * C + c0 + tx * 4) = p;
        }
    }
    __syncthreads();
    ushort_t* tp = outT + zoff;
#pragma unroll
    for (int j = 0; j < 4; j++) {
        const int cc = ty + j * 16;
        ushort4 o;
        o.x = f2b(tile[tx * 4 + 0][cc]);
        o.y = f2b(tile[tx * 4 + 1][cc]);
        o.z = f2b(tile[tx * 4 + 2][cc]);
        o.w = f2b(tile[tx * 4 + 3][cc]);
        *(ushort4*)(tp + (size_t)(c0 + cc) * R + r0 + tx * 4) = o;
    }
}

// LayerNorm over H=1024 (bf16 in, fp32 out), one block (256 thr) per row.
__global__ __launch_bounds__(256)
void ln_k(const ushort_t* __restrict__ Mt, const float* __restrict__ gamma,
          const float* __restrict__ beta, float* __restrict__ out)
{
    const size_t row = blockIdx.x;
    const int tid = threadIdx.x;
    const ushort4 u = *(const ushort4*)(Mt + row * 1024 + tid * 4);
    float x0 = b2f(u.x), x1 = b2f(u.y), x2 = b2f(u.z), x3 = b2f(u.w);
    float s  = x0 + x1 + x2 + x3;
    float s2 = x0 * x0 + x1 * x1 + x2 * x2 + x3 * x3;
#pragma unroll
    for (int off = 32; off > 0; off >>= 1) {
        s  += __shfl_down(s, off);
        s2 += __shfl_down(s2, off);
    }
    __shared__ float red[8];
    const int wave = tid >> 6, lane = tid & 63;
    if (lane == 0) { red[wave] = s; red[4 + wave] = s2; }
    __syncthreads();
    s  = red[0] + red[1] + red[2] + red[3];
    s2 = red[4] + red[5] + red[6] + red[7];
    const float mu  = s * (1.0f / 1024.0f);
    const float var = s2 * (1.0f / 1024.0f) - mu * mu;
    const float rinv = rsqrtf(var + 1e-12f);
    const float4 g = *(const float4*)(gamma + tid * 4);
    const float4 b = *(const float4*)(beta + tid * 4);
    float4 o;
    o.x = (x0 - mu) * rinv * g.x + b.x;
    o.y = (x1 - mu) * rinv * g.y + b.y;
    o.z = (x2 - mu) * rinv * g.z + b.z;
    o.w = (x3 - mu) * rinv * g.w + b.w;
    *(float4*)(out + row * 1024 + tid * 4) = o;
}

extern "C" void kernel_launch(void* const* d_in, const int* in_sizes, int n_in,
                              void* d_out, int out_size, void* d_ws, size_t ws_size,
                              hipStream_t stream)
{
    const float* X     = (const float*)d_in[0];  // [8,2048,1024]
    const float* masks = (const float*)d_in[1];  // [8,2048,2048]
    const float* Wm    = (const float*)d_in[2];  // [2048,1024]
    const float* bias  = (const float*)d_in[3];  // [1024]
    const float* gamma = (const float*)d_in[4];  // [1024]
    const float* beta  = (const float*)d_in[5];  // [1024]
    float* out = (float*)d_out;
    char* ws = (char*)d_ws;

    const int B = 8, S = 2048, H = 1024;

    // workspace layout (bytes): total 172,032,000
    ushort_t* Xb  = (ushort_t*)(ws);              // 33,554,432  X bf16 [B][S][H]
    ushort_t* XT  = (ushort_t*)(ws + 33554432);   // 33,554,432  X^T bf16 [B][H][S]
    ushort_t* WT  = (ushort_t*)(ws + 67108864);   //  4,194,304  W^T bf16 [H][2H]
    ushort_t* E   = (ushort_t*)(ws + 71303168);   // 67,108,864  exp(logits) bf16 [B][S][S]
    float*    rs  = (float*)   (ws + 138412032);  //     65,536  rowsums [B][S]
    ushort_t* CTX = (ushort_t*)(ws + 138477568);  // 33,554,432  context bf16 [B][S][H]
    unsigned char* X8 = (unsigned char*)CTX;      // alias: X8 dead before CTX written
    ushort_t* matching = E;                       // alias: E dead after GEMM2

    conv_trans<<<dim3(16, 32, 8), 256, 0, stream>>>(X, XT, Xb, X8, S, H);
    conv_trans<<<dim3(16, 32, 1), 256, 0, stream>>>(Wm, WT, nullptr, nullptr, 2 * H, H);
    hipMemsetAsync(rs, 0, (size_t)B * S * sizeof(float), stream);

    // GEMM1 (fp8, 128^2, ~3 blocks/CU): E = exp(mask(scale * X X^T)); rs += row sums
    gemm1_fp8<<<dim3(16, 16, 8), 256, 0, stream>>>(X8, masks, rs, E);

    // GEMM2 (bf16, 256x128, 2 blocks/CU): CTX = (E . XT^T) / rowsum
    gemm_bt<2><<<dim3(8, 8, 8), 512, 0, stream>>>(
        E, E, 1 << 30, XT,
        S, H, S, S, S, H,
        (long)S * S, (long)H * S, (long)S * H,
        rs, nullptr, CTX);

    // GEMM3 (bf16, 256x128, 2 blocks/CU): matching = [Xb|CTX] @ WT^T + bias -> bf16
    gemm_bt<3><<<dim3(64, 8, 1), 512, 0, stream>>>(
        Xb, CTX, H, WT,
        B * S, H, 2 * H, H, 2 * H, H,
        0, 0, 0,
        nullptr, bias, matching);

    ln_k<<<B * S, 256, 0, stream>>>(matching, gamma, beta, out);
}

// Round 7
// 473.073 us; speedup vs baseline: 1.0587x; 1.0587x over previous
//
#include <hip/hip_runtime.h>
#include <hip/hip_bf16.h>
#include <hip/hip_fp8.h>

// MatchingLayer: B=8, S=2048, H=1024
//   scores = (X X^T)/32 -> mask -> softmax -> context = P X
//   matching = [X|context] @ W + b -> LayerNorm
// Round-7 = round-6 resubmit (round-6 bench died on container acquire, not on
// the kernel; source re-audited for races/OOB — none found).
//   gemm1: round-0 128^2 fp8 kernel (proven fastest), epilogue = mask+exp+store
//          only (no rowsum/atomics).
//   gemm2/3: round-1 256^2 quad-buffered counted-vmcnt(8) kernel (best bf16);
//          gemm2 additionally computes rowsum in-kernel from its A-fragments
//          (sum_t E[s][t] over the K-loop), removing the memset launch and the
//          rs round-trip.
//   conv_trans: W-transpose folded in as grid z==8 (same 2048x1024 shape).
// WORKSPACE REQUIREMENT: 172,032,000 bytes (X8 aliases CTX region).

typedef unsigned short ushort_t;
typedef __attribute__((ext_vector_type(8))) short short8;
typedef __attribute__((ext_vector_type(4))) float float4v;

__device__ inline float b2f(unsigned int u) {
    union { unsigned int i; float f; } v; v.i = u << 16; return v.f;
}
__device__ inline ushort_t f2b(float f) {
    __hip_bfloat16 h = __float2bfloat16(f);
    return __builtin_bit_cast(ushort_t, h);
}
__device__ inline unsigned char f2e4(float f) {
    return __hip_fp8_e4m3(f).__x;
}

// async global->LDS DMA, 16B per lane; lds base wave-uniform, lane i -> lds+i*16.
__device__ inline void gload_lds16(const void* g, void* lds) {
    __builtin_amdgcn_global_load_lds(
        (const __attribute__((address_space(1))) unsigned int*)g,
        (__attribute__((address_space(3))) unsigned int*)lds, 16, 0, 0);
}

// ---------------- bf16 GEMM:  C[m][n] = sum_k A[m][k]*B[n][k] ----------------
// 256x256 tile, BK=32, quad-buffered LDS (128 KiB), 512 thr = 8 waves (2Mx4N).
// Counted vmcnt(8): tiles T+1,T+2 stay in flight across the barrier; never
// drained to 0 until the tail (round-1-verified structure, best measured).
// A dual-sourced at kSplit (for [X|ctx] concat).
// EPI 2: v / rowsum[row] -> bf16, rowsum computed IN-KERNEL from A-fragments
//        (each wave sums 2 of its 8 m-rows: (mi>>1)==(w&3); q-lane shfl
//        reduce; 1KB LDS broadcast).
// EPI 3: v + bias[col] -> bf16
template<int EPI>
__global__ __launch_bounds__(512, 2)
void gemm_bt(const ushort_t* __restrict__ A, const ushort_t* __restrict__ A2, int kSplit,
             const ushort_t* __restrict__ B,
             int M, int N, int K, int lda, int ldb, int ldc,
             long aBS, long bBS, long cBS,
             const float* __restrict__ bias,
             ushort_t* __restrict__ outb)
{
    // 4 buffers x (A 16KB + B 16KB) = 128 KiB
    __shared__ __align__(16) ushort_t smem[4 * 16384];

    const int tid = threadIdx.x;
    const int z = blockIdx.z;
    A  += (size_t)z * aBS;
    A2 += (size_t)z * aBS;
    B  += (size_t)z * bBS;
    outb += (size_t)z * cBS;

    const int bm = blockIdx.x * 256;
    const int bn = blockIdx.y * 256;
    const int w = tid >> 6, lane = tid & 63;
    const int wm = (w >> 2) * 128, wn = (w & 3) * 64;
    const int q = lane >> 4, l15 = lane & 15;
    // staging: per wave-call 64 lanes x 16B = 16 rows x 64B; row = p*16 + (lane>>2)
    const int srow = lane >> 2;
    // pre-swizzled source granule (elems): chunk = (lane&3) ^ ((row>>1)&3)
    const int schunk = ((lane & 3) ^ ((lane >> 3) & 3)) * 8;

    float4v acc[8][4];
#pragma unroll
    for (int i = 0; i < 8; i++)
#pragma unroll
        for (int j = 0; j < 4; j++) acc[i][j] = (float4v){0.f, 0.f, 0.f, 0.f};

    float rsum0 = 0.f, rsum1 = 0.f;   // EPI==2 row-sum partials (2 rows/wave-lane)

    const int NT = K >> 5;   // K-tiles of 32

#define STAGE(T) do {                                                               \
        const int k0_ = (T) * 32;                                                   \
        const ushort_t* aS_ = A; int ka_ = k0_;                                     \
        if (k0_ >= kSplit) { aS_ = A2; ka_ = k0_ - kSplit; }                        \
        ushort_t* buf_ = &smem[((T) & 3) * 16384];                                  \
        gload_lds16(aS_ + (size_t)(bm + w * 16       + srow) * lda + ka_ + schunk,  \
                    buf_ + w * 512);                                                \
        gload_lds16(aS_ + (size_t)(bm + (w + 8) * 16 + srow) * lda + ka_ + schunk,  \
                    buf_ + (w + 8) * 512);                                          \
        gload_lds16(B   + (size_t)(bn + w * 16       + srow) * ldb + k0_ + schunk,  \
                    buf_ + 8192 + w * 512);                                         \
        gload_lds16(B   + (size_t)(bn + (w + 8) * 16 + srow) * ldb + k0_ + schunk,  \
                    buf_ + 8192 + (w + 8) * 512);                                   \
    } while (0)

    // prologue: 3-deep prefetch (12 loads/thread outstanding)
    STAGE(0); STAGE(1); STAGE(2);

    for (int T = 0; T < NT; ++T) {
        // Own tile-T loads retired BEFORE the barrier => after the barrier all
        // waves' tile-T loads have landed. Counted: tiles T+1,T+2 (8 loads)
        // stay in flight across the barrier.
        if (T + 2 < NT)      asm volatile("s_waitcnt vmcnt(8)\n\ts_barrier" ::: "memory");
        else if (T + 1 < NT) asm volatile("s_waitcnt vmcnt(4)\n\ts_barrier" ::: "memory");
        else                 asm volatile("s_waitcnt vmcnt(0)\n\ts_barrier" ::: "memory");

        if (T + 3 < NT) STAGE(T + 3);

        const ushort_t* bufA = &smem[(T & 3) * 16384];
        const ushort_t* bufB = bufA + 8192;
        short8 af[8], bf[4];
#pragma unroll
        for (int mi = 0; mi < 8; mi++) {
            const int r = wm + mi * 16 + l15;
            af[mi] = *(const short8*)(&bufA[r * 32 + ((q ^ ((r >> 1) & 3)) << 3)]);
            if (EPI == 2 && (mi >> 1) == (w & 3)) {
                // this wave owns rows mi in {2(w&3), 2(w&3)+1}: accumulate E-row sum
                float s8 = 0.f;
#pragma unroll
                for (int e = 0; e < 8; e++) s8 += b2f((ushort_t)af[mi][e]);
                if (mi & 1) rsum1 += s8; else rsum0 += s8;
            }
        }
#pragma unroll
        for (int ni = 0; ni < 4; ni++) {
            const int r = wn + ni * 16 + l15;
            bf[ni] = *(const short8*)(&bufB[r * 32 + ((q ^ ((r >> 1) & 3)) << 3)]);
        }
        __builtin_amdgcn_s_setprio(1);
#pragma unroll
        for (int mi = 0; mi < 8; mi++)
#pragma unroll
            for (int ni = 0; ni < 4; ni++)
                acc[mi][ni] = __builtin_amdgcn_mfma_f32_16x16x32_bf16(
                    af[mi], bf[ni], acc[mi][ni], 0, 0, 0);
        __builtin_amdgcn_s_setprio(0);
    }
#undef STAGE

    float* rsld = (float*)smem;   // 256 floats, block-local rowsums (rows bm..bm+255)
    if (EPI == 2) {
        // q-lanes (l = q*16 + l15) hold disjoint K-granules of the same row: reduce
        rsum0 += __shfl_xor(rsum0, 16); rsum0 += __shfl_xor(rsum0, 32);
        rsum1 += __shfl_xor(rsum1, 16); rsum1 += __shfl_xor(rsum1, 32);
        if (lane < 16) {
            const int m0 = 2 * (w & 3);
            rsld[wm + m0 * 16 + l15]       = rsum0;
            rsld[wm + (m0 + 1) * 16 + l15] = rsum1;
        }
        __syncthreads();
    }

    // D layout (m89): col = lane&15, row = (lane>>4)*4 + reg
#pragma unroll
    for (int mi = 0; mi < 8; mi++) {
#pragma unroll
        for (int r = 0; r < 4; r++) {
            const int row = bm + wm + mi * 16 + q * 4 + r;
            const size_t ro = (size_t)row * ldc;
            float rsinv = 1.f;
            if (EPI == 2) rsinv = 1.0f / rsld[wm + mi * 16 + q * 4 + r];
#pragma unroll
            for (int ni = 0; ni < 4; ni++) {
                const int col = bn + wn + ni * 16 + l15;
                float v = acc[mi][ni][r];
                if (EPI == 2) outb[ro + col] = f2b(v * rsinv);
                else          outb[ro + col] = f2b(v + bias[col]);
            }
        }
    }
}

// ---------------- fp8 GEMM1: E = exp(mask(scale * X X^T)) ----------------
// Round-0 kernel (proven fastest): 128^2 tile, BK=128, 256 thr, 32 KB LDS,
// ~3 blocks/CU. Epilogue: mask + exp + store only (rowsum moved to gemm2).
__global__ __launch_bounds__(256, 2)
void gemm1_fp8(const unsigned char* __restrict__ X8,
               const float* __restrict__ mask,
               ushort_t* __restrict__ E)
{
    __shared__ __align__(16) unsigned char As[128 * 128];
    __shared__ __align__(16) unsigned char Bs[128 * 128];

    const int tid = threadIdx.x;
    const int z = blockIdx.z;
    const unsigned char* Xz = X8 + (size_t)z * 2048 * 1024;
    const float* mz = mask + (size_t)z * 2048 * 2048;
    ushort_t* Ez = E + (size_t)z * 2048 * 2048;

    const int bm = blockIdx.x * 128;
    const int bn = blockIdx.y * 128;
    const int wave = tid >> 6, lane = tid & 63;
    const int wm = (wave >> 1) * 64, wn = (wave & 1) * 64;
    const int q = lane >> 4, l15 = lane & 15;
    const int rx = l15 & 7;
    const int lrow = lane >> 3;
    const int cswz = (lane & 7) ^ lrow;       // 16B chunk 0..7 within 128B row

    float4v acc[4][4];
#pragma unroll
    for (int i = 0; i < 4; i++)
#pragma unroll
        for (int j = 0; j < 4; j++) acc[i][j] = (float4v){0.f, 0.f, 0.f, 0.f};

    for (int k0 = 0; k0 < 1024; k0 += 128) {
        // stage 128 rows x 128 B per matrix: 16 passes of 8 rows, wave w -> p=w*4..w*4+3
#pragma unroll
        for (int j = 0; j < 4; j++) {
            const int p = wave * 4 + j;
            const int ro = p * 8 + lrow;
            gload_lds16(Xz + (size_t)(bm + ro) * 1024 + k0 + cswz * 16, &As[p * 1024]);
            gload_lds16(Xz + (size_t)(bn + ro) * 1024 + k0 + cswz * 16, &Bs[p * 1024]);
        }
        __syncthreads();
#pragma unroll
        for (int kk = 0; kk < 128; kk += 32) {
            const int g = (kk >> 3) + q;                      // 8B granule 0..15
            const int co = (((g >> 1) ^ rx) << 4) + ((g & 1) << 3);
            long af[4], bfv[4];
#pragma unroll
            for (int mi = 0; mi < 4; mi++)
                af[mi] = *(const long*)(&As[(wm + mi * 16 + l15) * 128 + co]);
#pragma unroll
            for (int ni = 0; ni < 4; ni++)
                bfv[ni] = *(const long*)(&Bs[(wn + ni * 16 + l15) * 128 + co]);
#pragma unroll
            for (int mi = 0; mi < 4; mi++)
#pragma unroll
                for (int ni = 0; ni < 4; ni++)
                    acc[mi][ni] = __builtin_amdgcn_mfma_f32_16x16x32_fp8_fp8(
                        af[mi], bfv[ni], acc[mi][ni], 0, 0, 0);
        }
        __syncthreads();
    }

    const float scale = 0.03125f;  // 1/sqrt(1024)
#pragma unroll
    for (int mi = 0; mi < 4; mi++) {
#pragma unroll
        for (int r = 0; r < 4; r++) {
            const int row = bm + wm + mi * 16 + q * 4 + r;
            const size_t ro = (size_t)row * 2048;
#pragma unroll
            for (int ni = 0; ni < 4; ni++) {
                const int col = bn + wn + ni * 16 + l15;
                const float m = mz[ro + col];
                float v = __expf(acc[mi][ni][r] * scale * m - 1e9f * (1.0f - m));
                Ez[ro + col] = f2b(v);
            }
        }
    }
}

// fp32 [R][C] -> outT bf16 [C][R]; optional outS bf16 + outQ fp8 [R][C].
// z < 8: batched X slices. z == 8: W matrix (same 2048x1024 shape) -> WT only.
__global__ __launch_bounds__(256)
void conv_trans(const float* __restrict__ in, ushort_t* __restrict__ outT,
                ushort_t* __restrict__ outS, unsigned char* __restrict__ outQ,
                const float* __restrict__ inW, ushort_t* __restrict__ outTW,
                int R, int C)
{
    __shared__ float tile[64][65];
    const int tx = threadIdx.x & 15, ty = threadIdx.x >> 4;
    const int z = blockIdx.z;
    const float* src;
    ushort_t* dstT; ushort_t* dstS; unsigned char* dstQ;
    if (z == 8) {
        src = inW; dstT = outTW; dstS = nullptr; dstQ = nullptr;
    } else {
        const size_t zoff = (size_t)z * R * C;
        src = in + zoff; dstT = outT + zoff;
        dstS = outS + zoff; dstQ = outQ + zoff;
    }
    const int r0 = blockIdx.y * 64, c0 = blockIdx.x * 64;
#pragma unroll
    for (int j = 0; j < 4; j++) {
        const int r = ty + j * 16;
        const float4 v = *(const float4*)(src + (size_t)(r0 + r) * C + c0 + tx * 4);
        tile[r][tx * 4 + 0] = v.x;
        tile[r][tx * 4 + 1] = v.y;
        tile[r][tx * 4 + 2] = v.z;
        tile[r][tx * 4 + 3] = v.w;
        if (dstS) {
            ushort4 o;
            o.x = f2b(v.x); o.y = f2b(v.y); o.z = f2b(v.z); o.w = f2b(v.w);
            *(ushort4*)(dstS + (size_t)(r0 + r) * C + c0 + tx * 4) = o;
            uchar4 p;
            p.x = f2e4(v.x); p.y = f2e4(v.y); p.z = f2e4(v.z); p.w = f2e4(v.w);
            *(uchar4*)(dstQ + (size_t)(r0 + r) * C + c0 + tx * 4) = p;
        }
    }
    __syncthreads();
#pragma unroll
    for (int j = 0; j < 4; j++) {
        const int cc = ty + j * 16;
        ushort4 o;
        o.x = f2b(tile[tx * 4 + 0][cc]);
        o.y = f2b(tile[tx * 4 + 1][cc]);
        o.z = f2b(tile[tx * 4 + 2][cc]);
        o.w = f2b(tile[tx * 4 + 3][cc]);
        *(ushort4*)(dstT + (size_t)(c0 + cc) * R + r0 + tx * 4) = o;
    }
}

// LayerNorm over H=1024 (bf16 in, fp32 out), one block (256 thr) per row.
__global__ __launch_bounds__(256)
void ln_k(const ushort_t* __restrict__ Mt, const float* __restrict__ gamma,
          const float* __restrict__ beta, float* __restrict__ out)
{
    const size_t row = blockIdx.x;
    const int tid = threadIdx.x;
    const ushort4 u = *(const ushort4*)(Mt + row * 1024 + tid * 4);
    float x0 = b2f(u.x), x1 = b2f(u.y), x2 = b2f(u.z), x3 = b2f(u.w);
    float s  = x0 + x1 + x2 + x3;
    float s2 = x0 * x0 + x1 * x1 + x2 * x2 + x3 * x3;
#pragma unroll
    for (int off = 32; off > 0; off >>= 1) {
        s  += __shfl_down(s, off);
        s2 += __shfl_down(s2, off);
    }
    __shared__ float red[8];
    const int wave = tid >> 6, lane = tid & 63;
    if (lane == 0) { red[wave] = s; red[4 + wave] = s2; }
    __syncthreads();
    s  = red[0] + red[1] + red[2] + red[3];
    s2 = red[4] + red[5] + red[6] + red[7];
    const float mu  = s * (1.0f / 1024.0f);
    const float var = s2 * (1.0f / 1024.0f) - mu * mu;
    const float rinv = rsqrtf(var + 1e-12f);
    const float4 g = *(const float4*)(gamma + tid * 4);
    const float4 b = *(const float4*)(beta + tid * 4);
    float4 o;
    o.x = (x0 - mu) * rinv * g.x + b.x;
    o.y = (x1 - mu) * rinv * g.y + b.y;
    o.z = (x2 - mu) * rinv * g.z + b.z;
    o.w = (x3 - mu) * rinv * g.w + b.w;
    *(float4*)(out + row * 1024 + tid * 4) = o;
}

extern "C" void kernel_launch(void* const* d_in, const int* in_sizes, int n_in,
                              void* d_out, int out_size, void* d_ws, size_t ws_size,
                              hipStream_t stream)
{
    const float* X     = (const float*)d_in[0];  // [8,2048,1024]
    const float* masks = (const float*)d_in[1];  // [8,2048,2048]
    const float* Wm    = (const float*)d_in[2];  // [2048,1024]
    const float* bias  = (const float*)d_in[3];  // [1024]
    const float* gamma = (const float*)d_in[4];  // [1024]
    const float* beta  = (const float*)d_in[5];  // [1024]
    float* out = (float*)d_out;
    char* ws = (char*)d_ws;

    const int B = 8, S = 2048, H = 1024;

    // workspace layout (bytes): total 172,032,000
    ushort_t* Xb  = (ushort_t*)(ws);              // 33,554,432  X bf16 [B][S][H]
    ushort_t* XT  = (ushort_t*)(ws + 33554432);   // 33,554,432  X^T bf16 [B][H][S]
    ushort_t* WT  = (ushort_t*)(ws + 67108864);   //  4,194,304  W^T bf16 [H][2H]
    ushort_t* E   = (ushort_t*)(ws + 71303168);   // 67,108,864  exp(logits) bf16 [B][S][S]
    ushort_t* CTX = (ushort_t*)(ws + 138477568);  // 33,554,432  context bf16 [B][S][H]
    unsigned char* X8 = (unsigned char*)CTX;      // alias: X8 dead before CTX written
    ushort_t* matching = E;                       // alias: E dead after GEMM2

    // transposes + dtype conversions (z==8 handles W -> WT)
    conv_trans<<<dim3(16, 32, 9), 256, 0, stream>>>(X, XT, Xb, X8, Wm, WT, S, H);

    // GEMM1 (fp8, 128^2): E = exp(mask(scale * X X^T))
    gemm1_fp8<<<dim3(16, 16, 8), 256, 0, stream>>>(X8, masks, E);

    // GEMM2 (bf16, 256^2 quad-buffer): CTX = (E . XT^T) / rowsum(E), rowsum in-kernel
    gemm_bt<2><<<dim3(8, 4, 8), 512, 0, stream>>>(
        E, E, 1 << 30, XT,
        S, H, S, S, S, H,
        (long)S * S, (long)H * S, (long)S * H,
        nullptr, CTX);

    // GEMM3 (bf16, 256^2 quad-buffer): matching = [Xb|CTX] @ WT^T + bias -> bf16
    gemm_bt<3><<<dim3(64, 4, 1), 512, 0, stream>>>(
        Xb, CTX, H, WT,
        B * S, H, 2 * H, H, 2 * H, H,
        0, 0, 0,
        bias, matching);

    ln_k<<<B * S, 256, 0, stream>>>(matching, gamma, beta, out);
}